// Round 3
// baseline (2028.148 us; speedup 1.0000x reference)
//
#include <hip/hip_runtime.h>
#include <math.h>

#define TT 10
#define BB 32
#define CIN 3
#define COUT 64
#define HH 64
#define WW 64
#define HW (HH*WW)           // 4096
#define DECAY 0.2f
#define INH 1.625f

__device__ __forceinline__ unsigned int enc_f(float f) {
    unsigned int u = __float_as_uint(f);
    return (u & 0x80000000u) ? ~u : (u | 0x80000000u);
}
__device__ __forceinline__ float dec_f(unsigned int u) {
    u = (u & 0x80000000u) ? (u & 0x7FFFFFFFu) : ~u;
    return __uint_as_float(u);
}

// ---------------------------------------------------------------------------
// Pass 1: conv for the threshold max ONLY — no i stores (compute-bound).
// Same FMA ordering as pass 2 -> bitwise-identical i values.
// lane = channel (W[27] in VGPRs), wave = row within a 4-row group.
// Grid (16 rowgroups, B, T) x 256.
// ---------------------------------------------------------------------------
__global__ __launch_bounds__(256) void thr_kernel(
    const float* __restrict__ x,        // (T,B,3,64,64)
    const float* __restrict__ Wt,       // (64,3,3,3)
    unsigned int* __restrict__ thr_raw) // (T,64) pre-zeroed
{
    __shared__ float sx[CIN][6][68];    // row stride 68 -> 16B-aligned rows
    __shared__ float wmax[4][COUT];

    const int tid  = threadIdx.x;
    const int lane = tid & 63;          // channel
    const int wave = tid >> 6;          // row within 4-row group
    const int h0   = blockIdx.x * 4;
    const int b    = blockIdx.y;
    const int t    = blockIdx.z;

    float w[27];
    #pragma unroll
    for (int k = 0; k < 27; k++) w[k] = Wt[lane * 27 + k];

    // stage x tile (3 x 6 x 66 used cols), coalesced, zero-padded
    const float* xb = x + ((size_t)t * BB + b) * (CIN * HW);
    for (int l = tid; l < CIN * 6 * 66; l += 256) {
        int ci  = l / 396;
        int r   = (l % 396) / 66;
        int col = l % 66;
        int gh = h0 + r - 1;
        int gw = col - 1;
        float v = 0.f;
        if (gh >= 0 && gh < HH && gw >= 0 && gw < WW)
            v = xb[ci * HW + gh * WW + gw];
        sx[ci][r][col] = v;
    }
    __syncthreads();

    float mx = -INFINITY;

    for (int cc = 0; cc < 16; cc++) {          // 4-pixel chunks along the row
        float acc0 = 0.f, acc1 = 0.f, acc2 = 0.f, acc3 = 0.f;
        #pragma unroll
        for (int ci = 0; ci < CIN; ci++)
            #pragma unroll
            for (int kh = 0; kh < 3; kh++) {
                // wave-uniform LDS reads: broadcast, conflict-free
                const float* rp = &sx[ci][wave + kh][cc * 4];
                float4 q = *(const float4*)rp;
                float2 r2 = *(const float2*)(rp + 4);
                float x0 = q.x, x1 = q.y, x2 = q.z, x3 = q.w;
                float x4 = r2.x, x5 = r2.y;
                const float w0 = w[ci * 9 + kh * 3 + 0];
                const float w1 = w[ci * 9 + kh * 3 + 1];
                const float w2 = w[ci * 9 + kh * 3 + 2];
                acc0 = fmaf(w0, x0, acc0); acc0 = fmaf(w1, x1, acc0); acc0 = fmaf(w2, x2, acc0);
                acc1 = fmaf(w0, x1, acc1); acc1 = fmaf(w1, x2, acc1); acc1 = fmaf(w2, x3, acc1);
                acc2 = fmaf(w0, x2, acc2); acc2 = fmaf(w1, x3, acc2); acc2 = fmaf(w2, x4, acc2);
                acc3 = fmaf(w0, x3, acc3); acc3 = fmaf(w1, x4, acc3); acc3 = fmaf(w2, x5, acc3);
            }
        mx = fmaxf(mx, fmaxf(fmaxf(acc0, acc1), fmaxf(acc2, acc3)));
    }

    wmax[wave][lane] = mx;
    __syncthreads();
    if (wave == 0) {
        float m = fmaxf(fmaxf(wmax[0][lane], wmax[1][lane]),
                        fmaxf(wmax[2][lane], wmax[3][lane]));
        atomicMax(&thr_raw[t * COUT + lane], enc_f(m));
    }
}

// ---------------------------------------------------------------------------
// Pass 2: fused conv + LIF, barrier-free t-loop, direct-value output.
// x rows (h-1..h+1) staged 5 time steps at a time (12.2 KB LDS -> 8 blk/CU,
// grid 2048 = 256 CU x 8 fills in one generation). Output slab written ONCE
// per t directly from registers (0/1 from fmask bits): no zero-fill, no
// sparse RMW stores, no ordering hazard -> no barriers inside the t-loop.
// Stores coalesced via in-register shfl transpose: each float4 store covers
// 16 full 64B lines (4-lane 64B segments per channel row).
// Same FMA order as pass 1 -> bitwise-identical i. Grid = B*H = 2048 x 256.
// ---------------------------------------------------------------------------
__global__ __launch_bounds__(256, 8) void fused_kernel(
    const float* __restrict__ x,              // (T,B,3,64,64)
    const float* __restrict__ Wt,             // (64,3,3,3)
    const unsigned int* __restrict__ thr_raw, // (T,64)
    float* __restrict__ out)                  // (T,B,64,64,64)
{
    __shared__ float sx[5][CIN][3][68];       // 12,240 B; rows 16B-aligned

    const int tid  = threadIdx.x;
    const int lane = tid & 63;                            // channel
    const int wave = tid >> 6;
    const int p0   = __builtin_amdgcn_readfirstlane(wave * 16);
    const int b    = blockIdx.x >> 6;
    const int h    = blockIdx.x & 63;

    float w[27];
    #pragma unroll
    for (int k = 0; k < 27; k++) w[k] = Wt[lane * 27 + k];

    const float* xb0 = x + (size_t)b * (CIN * HW);        // t=0 base, this b

#define STAGE5(T0) {                                                          \
        for (int l = tid; l < 5 * 594; l += 256) {                            \
            int t   = l / 594;                                                \
            int r0  = l - t * 594;                                            \
            int ci  = r0 / 198;                                               \
            int r1  = r0 - ci * 198;                                          \
            int r   = r1 / 66;                                                \
            int col = r1 - r * 66;                                            \
            int gh = h + r - 1;                                               \
            int gw = col - 1;                                                 \
            float v = 0.f;                                                    \
            if (gh >= 0 && gh < HH && gw >= 0 && gw < WW)                     \
                v = xb0[(size_t)((T0) + t) * ((size_t)BB * CIN * HW)          \
                        + ci * HW + gh * WW + gw];                            \
            sx[t][ci][r][col] = v;                                            \
        }                                                                     \
    }

    STAGE5(0);

    float mem[16];
    #pragma unroll
    for (int j = 0; j < 16; j++) mem[j] = 0.f;

    __syncthreads();   // first 5 t staged

    #pragma unroll 1
    for (int t = 0; t < TT; t++) {
        if (t == 5) {               // restage second half (only 2 barriers)
            __syncthreads();
            STAGE5(5);
            __syncthreads();
        }
        const int slot = (t < 5) ? t : t - 5;

        // per-lane (= per-channel) threshold constants (L2-resident 2.5 KB)
        float thr   = dec_f(thr_raw[t * COUT + lane]) + 1e-4f;
        float sinv  = 8.0f / thr;
        float s04   = 0.4f * thr;
        float sinh_ = INH * thr;

        int fmask = 0;     // bit j: this lane's channel fired at pixel p0+j

#define LIF_PX(J, ACC) {                                                    \
        float cur = fmaxf(ACC, 0.f);                                        \
        float z   = (cur - s04) * sinv;                                     \
        float sig = 1.0f / (1.0f + expf(-z));                               \
        float m   = mem[J] * DECAY + thr * sig;                             \
        int   sp  = m > thr;                                                \
        float score = sp ? m : 0.f;                                         \
        unsigned long long blt = __ballot(sp);                              \
        int fr = 0, sp_any = 0;                                             \
        if (blt) {   /* wave-uniform; rare */                               \
            float bs = score;                                               \
            int   bc = lane;                                                \
            _Pragma("unroll")                                               \
            for (int off = 32; off > 0; off >>= 1) {                        \
                float so = __shfl_xor(bs, off, 64);                         \
                int   co = __shfl_xor(bc, off, 64);                         \
                if (so > bs || (so == bs && co < bc)) { bs = so; bc = co; } \
            }                                                               \
            int spw = __shfl(sp, bc, 64);   /* winner's spike = any_sp */   \
            fr     = (lane == bc) && sp;                                    \
            sp_any = spw;                                                   \
        }                                                                   \
        mem[J] = fr ? 0.f : (m - (sp_any ? sinh_ : 0.f));                   \
        if (fr) fmask |= (1 << (J));                                        \
    }

        #pragma unroll
        for (int ch = 0; ch < 4; ch++) {       // 4-pixel chunks of this wave
            const int c0 = p0 + ch * 4;        // chunk start pixel
            float acc0 = 0.f, acc1 = 0.f, acc2 = 0.f, acc3 = 0.f;
            #pragma unroll
            for (int ci = 0; ci < CIN; ci++)
                #pragma unroll
                for (int kh = 0; kh < 3; kh++) {
                    // wave-uniform LDS reads: broadcast, conflict-free
                    const float* rp = &sx[slot][ci][kh][c0];
                    float4 q = *(const float4*)rp;
                    float2 r2 = *(const float2*)(rp + 4);
                    float x0 = q.x, x1 = q.y, x2 = q.z, x3 = q.w;
                    float x4 = r2.x, x5 = r2.y;
                    const float w0 = w[ci * 9 + kh * 3 + 0];
                    const float w1 = w[ci * 9 + kh * 3 + 1];
                    const float w2 = w[ci * 9 + kh * 3 + 2];
                    acc0 = fmaf(w0, x0, acc0); acc0 = fmaf(w1, x1, acc0); acc0 = fmaf(w2, x2, acc0);
                    acc1 = fmaf(w0, x1, acc1); acc1 = fmaf(w1, x2, acc1); acc1 = fmaf(w2, x3, acc1);
                    acc2 = fmaf(w0, x2, acc2); acc2 = fmaf(w1, x3, acc2); acc2 = fmaf(w2, x4, acc2);
                    acc3 = fmaf(w0, x3, acc3); acc3 = fmaf(w1, x4, acc3); acc3 = fmaf(w2, x5, acc3);
                }
            LIF_PX(ch * 4 + 0, acc0);
            LIF_PX(ch * 4 + 1, acc1);
            LIF_PX(ch * 4 + 2, acc2);
            LIF_PX(ch * 4 + 3, acc3);
        }
#undef LIF_PX

        // Direct-value output: shfl-transpose fmask bits so each float4
        // store instruction covers 16 FULL 64B lines (4 lanes = one 64B
        // segment of one channel row). One store per address, no RMW.
        float* os = out + (((size_t)t * BB + b) * COUT) * HW + h * WW;
        #pragma unroll
        for (int k = 0; k < 4; k++) {
            const int c   = k * 16 + (lane >> 2);        // channel
            const int pix = (lane & 3) * 4;              // pixel offset
            int fm  = __shfl(fmask, c, 64);              // bits of channel c
            int nib = (fm >> pix) & 0xF;
            float4 v;
            v.x = (nib & 1) ? 1.f : 0.f;
            v.y = (nib & 2) ? 1.f : 0.f;
            v.z = (nib & 4) ? 1.f : 0.f;
            v.w = (nib & 8) ? 1.f : 0.f;
            *(float4*)(os + (size_t)c * HW + p0 + pix) = v;
        }
    }
#undef STAGE5
}

// ---------------------------------------------------------------------------
extern "C" void kernel_launch(void* const* d_in, const int* in_sizes, int n_in,
                              void* d_out, int out_size, void* d_ws, size_t ws_size,
                              hipStream_t stream) {
    const float* x = (const float*)d_in[0];   // (T,B,3,64,64)
    const float* W = (const float*)d_in[1];   // (64,3,3,3)
    float* out     = (float*)d_out;           // (T,B,64,64,64)

    unsigned int* thr = (unsigned int*)d_ws;  // (T,64) — only 2.5 KB of ws used
    hipMemsetAsync(thr, 0, TT * COUT * sizeof(unsigned int), stream);

    thr_kernel<<<dim3(HH / 4, BB, TT), 256, 0, stream>>>(x, W, thr);
    fused_kernel<<<dim3(BB * HH), 256, 0, stream>>>(x, W, thr, out);
}

// Round 4
// 1629.671 us; speedup vs baseline: 1.2445x; 1.2445x over previous
//
#include <hip/hip_runtime.h>
#include <math.h>

#define TT 10
#define BB 32
#define CIN 3
#define COUT 64
#define HH 64
#define WW 64
#define HW (HH*WW)           // 4096
#define DECAY 0.2f
#define INH 1.625f

__device__ __forceinline__ unsigned int enc_f(float f) {
    unsigned int u = __float_as_uint(f);
    return (u & 0x80000000u) ? ~u : (u | 0x80000000u);
}
__device__ __forceinline__ float dec_f(unsigned int u) {
    u = (u & 0x80000000u) ? (u & 0x7FFFFFFFu) : ~u;
    return __uint_as_float(u);
}

// ---------------------------------------------------------------------------
// Pass 1: conv for the threshold max ONLY — no i stores (compute-bound).
// Same FMA ordering as pass 2 -> bitwise-identical i values.
// lane = channel (W[27] in VGPRs), wave = row within a 4-row group.
// Grid (16 rowgroups, B, T) x 256.
// ---------------------------------------------------------------------------
__global__ __launch_bounds__(256) void thr_kernel(
    const float* __restrict__ x,        // (T,B,3,64,64)
    const float* __restrict__ Wt,       // (64,3,3,3)
    unsigned int* __restrict__ thr_raw) // (T,64) pre-zeroed
{
    __shared__ float sx[CIN][6][68];    // row stride 68 -> 16B-aligned rows
    __shared__ float wmax[4][COUT];

    const int tid  = threadIdx.x;
    const int lane = tid & 63;          // channel
    const int wave = tid >> 6;          // row within 4-row group
    const int h0   = blockIdx.x * 4;
    const int b    = blockIdx.y;
    const int t    = blockIdx.z;

    float w[27];
    #pragma unroll
    for (int k = 0; k < 27; k++) w[k] = Wt[lane * 27 + k];

    // stage x tile (3 x 6 x 66 used cols), coalesced, zero-padded
    const float* xb = x + ((size_t)t * BB + b) * (CIN * HW);
    for (int l = tid; l < CIN * 6 * 66; l += 256) {
        int ci  = l / 396;
        int r   = (l % 396) / 66;
        int col = l % 66;
        int gh = h0 + r - 1;
        int gw = col - 1;
        float v = 0.f;
        if (gh >= 0 && gh < HH && gw >= 0 && gw < WW)
            v = xb[ci * HW + gh * WW + gw];
        sx[ci][r][col] = v;
    }
    __syncthreads();

    float mx = -INFINITY;

    for (int cc = 0; cc < 16; cc++) {          // 4-pixel chunks along the row
        float acc0 = 0.f, acc1 = 0.f, acc2 = 0.f, acc3 = 0.f;
        #pragma unroll
        for (int ci = 0; ci < CIN; ci++)
            #pragma unroll
            for (int kh = 0; kh < 3; kh++) {
                // wave-uniform LDS reads: broadcast, conflict-free
                const float* rp = &sx[ci][wave + kh][cc * 4];
                float4 q = *(const float4*)rp;
                float2 r2 = *(const float2*)(rp + 4);
                float x0 = q.x, x1 = q.y, x2 = q.z, x3 = q.w;
                float x4 = r2.x, x5 = r2.y;
                const float w0 = w[ci * 9 + kh * 3 + 0];
                const float w1 = w[ci * 9 + kh * 3 + 1];
                const float w2 = w[ci * 9 + kh * 3 + 2];
                acc0 = fmaf(w0, x0, acc0); acc0 = fmaf(w1, x1, acc0); acc0 = fmaf(w2, x2, acc0);
                acc1 = fmaf(w0, x1, acc1); acc1 = fmaf(w1, x2, acc1); acc1 = fmaf(w2, x3, acc1);
                acc2 = fmaf(w0, x2, acc2); acc2 = fmaf(w1, x3, acc2); acc2 = fmaf(w2, x4, acc2);
                acc3 = fmaf(w0, x3, acc3); acc3 = fmaf(w1, x4, acc3); acc3 = fmaf(w2, x5, acc3);
            }
        mx = fmaxf(mx, fmaxf(fmaxf(acc0, acc1), fmaxf(acc2, acc3)));
    }

    wmax[wave][lane] = mx;
    __syncthreads();
    if (wave == 0) {
        float m = fmaxf(fmaxf(wmax[0][lane], wmax[1][lane]),
                        fmaxf(wmax[2][lane], wmax[3][lane]));
        atomicMax(&thr_raw[t * COUT + lane], enc_f(m));
    }
}

// ---------------------------------------------------------------------------
// Pass 2: fused conv + LIF, sparse-store-only output.
// out is pre-zeroed by ONE contiguous hipMemsetAsync (proven clean/fast
// pattern); the kernel stores ONLY winner spikes (rare 4B stores, unique
// addresses, no ordering hazard) -> no zero-fill, no per-t barriers.
// x rows (h-1..h+1) staged 5 time steps at a time (12.2 KB LDS -> 8 blk/CU).
// Same FMA order as pass 1 -> bitwise-identical i. Grid = B*H = 2048 x 256.
// ---------------------------------------------------------------------------
__global__ __launch_bounds__(256, 8) void fused_kernel(
    const float* __restrict__ x,              // (T,B,3,64,64)
    const float* __restrict__ Wt,             // (64,3,3,3)
    const unsigned int* __restrict__ thr_raw, // (T,64)
    float* __restrict__ out)                  // (T,B,64,64,64) pre-zeroed
{
    __shared__ float sx[5][CIN][3][68];       // 12,240 B; rows 16B-aligned

    const int tid  = threadIdx.x;
    const int lane = tid & 63;                            // channel
    const int wave = tid >> 6;
    const int p0   = __builtin_amdgcn_readfirstlane(wave * 16);
    const int b    = blockIdx.x >> 6;
    const int h    = blockIdx.x & 63;

    float w[27];
    #pragma unroll
    for (int k = 0; k < 27; k++) w[k] = Wt[lane * 27 + k];

    const float* xb0 = x + (size_t)b * (CIN * HW);        // t=0 base, this b

#define STAGE5(T0) {                                                          \
        for (int l = tid; l < 5 * 594; l += 256) {                            \
            int t   = l / 594;                                                \
            int r0  = l - t * 594;                                            \
            int ci  = r0 / 198;                                               \
            int r1  = r0 - ci * 198;                                          \
            int r   = r1 / 66;                                                \
            int col = r1 - r * 66;                                            \
            int gh = h + r - 1;                                               \
            int gw = col - 1;                                                 \
            float v = 0.f;                                                    \
            if (gh >= 0 && gh < HH && gw >= 0 && gw < WW)                     \
                v = xb0[(size_t)((T0) + t) * ((size_t)BB * CIN * HW)          \
                        + ci * HW + gh * WW + gw];                            \
            sx[t][ci][r][col] = v;                                            \
        }                                                                     \
    }

    STAGE5(0);

    float mem[16];
    #pragma unroll
    for (int j = 0; j < 16; j++) mem[j] = 0.f;

    __syncthreads();   // first 5 t staged

    #pragma unroll 1
    for (int t = 0; t < TT; t++) {
        if (t == 5) {               // restage second half (only 2 barriers)
            __syncthreads();
            STAGE5(5);
            __syncthreads();
        }
        const int slot = (t < 5) ? t : t - 5;

        // per-lane (= per-channel) threshold constants (L2-resident 2.5 KB)
        float thr   = dec_f(thr_raw[t * COUT + lane]) + 1e-4f;
        float sinv  = 8.0f / thr;
        float s04   = 0.4f * thr;
        float sinh_ = INH * thr;

        int fmask = 0;     // bit j: this lane's channel fired at pixel p0+j

#define LIF_PX(J, ACC) {                                                    \
        float cur = fmaxf(ACC, 0.f);                                        \
        float z   = (cur - s04) * sinv;                                     \
        float sig = 1.0f / (1.0f + expf(-z));                               \
        float m   = mem[J] * DECAY + thr * sig;                             \
        int   sp  = m > thr;                                                \
        float score = sp ? m : 0.f;                                         \
        unsigned long long blt = __ballot(sp);                              \
        int fr = 0, sp_any = 0;                                             \
        if (blt) {   /* wave-uniform; rare */                               \
            float bs = score;                                               \
            int   bc = lane;                                                \
            _Pragma("unroll")                                               \
            for (int off = 32; off > 0; off >>= 1) {                        \
                float so = __shfl_xor(bs, off, 64);                         \
                int   co = __shfl_xor(bc, off, 64);                         \
                if (so > bs || (so == bs && co < bc)) { bs = so; bc = co; } \
            }                                                               \
            int spw = __shfl(sp, bc, 64);   /* winner's spike = any_sp */   \
            fr     = (lane == bc) && sp;                                    \
            sp_any = spw;                                                   \
        }                                                                   \
        mem[J] = fr ? 0.f : (m - (sp_any ? sinh_ : 0.f));                   \
        if (fr) fmask |= (1 << (J));                                        \
    }

        #pragma unroll
        for (int ch = 0; ch < 4; ch++) {       // 4-pixel chunks of this wave
            const int c0 = p0 + ch * 4;        // chunk start pixel
            float acc0 = 0.f, acc1 = 0.f, acc2 = 0.f, acc3 = 0.f;
            #pragma unroll
            for (int ci = 0; ci < CIN; ci++)
                #pragma unroll
                for (int kh = 0; kh < 3; kh++) {
                    // wave-uniform LDS reads: broadcast, conflict-free
                    const float* rp = &sx[slot][ci][kh][c0];
                    float4 q = *(const float4*)rp;
                    float2 r2 = *(const float2*)(rp + 4);
                    float x0 = q.x, x1 = q.y, x2 = q.z, x3 = q.w;
                    float x4 = r2.x, x5 = r2.y;
                    const float w0 = w[ci * 9 + kh * 3 + 0];
                    const float w1 = w[ci * 9 + kh * 3 + 1];
                    const float w2 = w[ci * 9 + kh * 3 + 2];
                    acc0 = fmaf(w0, x0, acc0); acc0 = fmaf(w1, x1, acc0); acc0 = fmaf(w2, x2, acc0);
                    acc1 = fmaf(w0, x1, acc1); acc1 = fmaf(w1, x2, acc1); acc1 = fmaf(w2, x3, acc1);
                    acc2 = fmaf(w0, x2, acc2); acc2 = fmaf(w1, x3, acc2); acc2 = fmaf(w2, x4, acc2);
                    acc3 = fmaf(w0, x3, acc3); acc3 = fmaf(w1, x4, acc3); acc3 = fmaf(w2, x5, acc3);
                }
            LIF_PX(ch * 4 + 0, acc0);
            LIF_PX(ch * 4 + 1, acc1);
            LIF_PX(ch * 4 + 2, acc2);
            LIF_PX(ch * 4 + 3, acc3);
        }
#undef LIF_PX

        // sparse winner stores (rare); out pre-zeroed by memset; each
        // address written by exactly one thread -> no ordering needed
        if (fmask) {
            float* os = out + (((size_t)t * BB + b) * COUT) * HW + h * WW;
            #pragma unroll
            for (int j = 0; j < 16; j++)
                if (fmask & (1 << j))
                    os[(size_t)lane * HW + p0 + j] = 1.0f;
        }
    }
#undef STAGE5
}

// ---------------------------------------------------------------------------
extern "C" void kernel_launch(void* const* d_in, const int* in_sizes, int n_in,
                              void* d_out, int out_size, void* d_ws, size_t ws_size,
                              hipStream_t stream) {
    const float* x = (const float*)d_in[0];   // (T,B,3,64,64)
    const float* W = (const float*)d_in[1];   // (64,3,3,3)
    float* out     = (float*)d_out;           // (T,B,64,64,64)

    unsigned int* thr = (unsigned int*)d_ws;  // (T,64) — only 2.5 KB of ws used
    hipMemsetAsync(thr, 0, TT * COUT * sizeof(unsigned int), stream);
    // contiguous zero of the whole output (proven 6.2 TB/s fill pattern);
    // fused_kernel then stores only the sparse winner spikes
    hipMemsetAsync(out, 0, (size_t)out_size, stream);

    thr_kernel<<<dim3(HH / 4, BB, TT), 256, 0, stream>>>(x, W, thr);
    fused_kernel<<<dim3(BB * HH), 256, 0, stream>>>(x, W, thr, out);
}

// Round 5
// 543.555 us; speedup vs baseline: 3.7313x; 2.9982x over previous
//
#include <hip/hip_runtime.h>
#include <math.h>

#define TT 10
#define BB 32
#define CIN 3
#define COUT 64
#define HH 64
#define WW 64
#define HW (HH*WW)           // 4096
#define DECAY 0.2f
#define INH 1.625f

__device__ __forceinline__ unsigned int enc_f(float f) {
    unsigned int u = __float_as_uint(f);
    return (u & 0x80000000u) ? ~u : (u | 0x80000000u);
}
__device__ __forceinline__ float dec_f(unsigned int u) {
    u = (u & 0x80000000u) ? (u & 0x7FFFFFFFu) : ~u;
    return __uint_as_float(u);
}

// ---------------------------------------------------------------------------
// Pass 1: conv for the threshold max + coalesced zero-fill of the output.
// Grid (16 rowgroups, B, T) exactly tiles out[t][b][:][h0:h0+4][:]; the
// zero stores (full 256B segments per 16-lane group) are issued before the
// conv loop so they drain under ~90us of VALU work — no separate memset.
// Same FMA ordering as pass 2 -> bitwise-identical i values.
// lane = channel (W[27] in VGPRs), wave = row within a 4-row group.
// NOTE: plain __launch_bounds__(256) — no min-occupancy arg. Rounds 2-4
// used (256,6)/(256,8), which capped VGPRs at 40/32 and spilled w[27]+
// mem[16] to scratch: ~6 GB of HBM traffic, 2-3x regression.
// ---------------------------------------------------------------------------
__global__ __launch_bounds__(256) void thr_kernel(
    const float* __restrict__ x,        // (T,B,3,64,64)
    const float* __restrict__ Wt,       // (64,3,3,3)
    unsigned int* __restrict__ thr_raw, // (T,64) pre-zeroed
    float* __restrict__ out)            // (T,B,64,64,64) — zero-filled here
{
    __shared__ float sx[CIN][6][68];    // row stride 68 -> 16B-aligned rows
    __shared__ float wmax[4][COUT];

    const int tid  = threadIdx.x;
    const int lane = tid & 63;          // channel
    const int wave = tid >> 6;          // row within 4-row group
    const int h0   = blockIdx.x * 4;
    const int b    = blockIdx.y;
    const int t    = blockIdx.z;

    float w[27];
    #pragma unroll
    for (int k = 0; k < 27; k++) w[k] = Wt[lane * 27 + k];

    // stage x tile (3 x 6 x 66 used cols), coalesced, zero-padded
    const float* xb = x + ((size_t)t * BB + b) * (CIN * HW);
    for (int l = tid; l < CIN * 6 * 66; l += 256) {
        int ci  = l / 396;
        int r   = (l % 396) / 66;
        int col = l % 66;
        int gh = h0 + r - 1;
        int gw = col - 1;
        float v = 0.f;
        if (gh >= 0 && gh < HH && gw >= 0 && gw < WW)
            v = xb[ci * HW + gh * WW + gw];
        sx[ci][r][col] = v;
    }

    // coalesced zero-fill of out[t][b][:][h0:h0+4][:] (64 KB / block).
    // 16 float4 per row-of-64; 16 lanes cover a 256B segment (4 full lines).
    {
        float* ob = out + (((size_t)t * BB + b) * COUT) * HW;
        #pragma unroll
        for (int g = 0; g < 16; g++) {
            int l   = g * 256 + tid;          // 0..4095 float4s
            int row = l >> 4;                 // 0..255 = (c<<2)|hr
            int q   = l & 15;                 // float4 within row
            int c   = row >> 2;
            int hr  = row & 3;
            *(float4*)(ob + (size_t)c * HW + (h0 + hr) * WW + q * 4) =
                make_float4(0.f, 0.f, 0.f, 0.f);
        }
    }

    __syncthreads();

    float mx = -INFINITY;

    for (int cc = 0; cc < 16; cc++) {          // 4-pixel chunks along the row
        float acc0 = 0.f, acc1 = 0.f, acc2 = 0.f, acc3 = 0.f;
        #pragma unroll
        for (int ci = 0; ci < CIN; ci++)
            #pragma unroll
            for (int kh = 0; kh < 3; kh++) {
                // wave-uniform LDS reads: broadcast, conflict-free
                const float* rp = &sx[ci][wave + kh][cc * 4];
                float4 q = *(const float4*)rp;
                float2 r2 = *(const float2*)(rp + 4);
                float x0 = q.x, x1 = q.y, x2 = q.z, x3 = q.w;
                float x4 = r2.x, x5 = r2.y;
                const float w0 = w[ci * 9 + kh * 3 + 0];
                const float w1 = w[ci * 9 + kh * 3 + 1];
                const float w2 = w[ci * 9 + kh * 3 + 2];
                acc0 = fmaf(w0, x0, acc0); acc0 = fmaf(w1, x1, acc0); acc0 = fmaf(w2, x2, acc0);
                acc1 = fmaf(w0, x1, acc1); acc1 = fmaf(w1, x2, acc1); acc1 = fmaf(w2, x3, acc1);
                acc2 = fmaf(w0, x2, acc2); acc2 = fmaf(w1, x3, acc2); acc2 = fmaf(w2, x4, acc2);
                acc3 = fmaf(w0, x3, acc3); acc3 = fmaf(w1, x4, acc3); acc3 = fmaf(w2, x5, acc3);
            }
        mx = fmaxf(mx, fmaxf(fmaxf(acc0, acc1), fmaxf(acc2, acc3)));
    }

    wmax[wave][lane] = mx;
    __syncthreads();
    if (wave == 0) {
        float m = fmaxf(fmaxf(wmax[0][lane], wmax[1][lane]),
                        fmaxf(wmax[2][lane], wmax[3][lane]));
        atomicMax(&thr_raw[t * COUT + lane], enc_f(m));
    }
}

// ---------------------------------------------------------------------------
// Pass 2: fused conv + LIF, sparse-store-only output.
// out pre-zeroed by thr_kernel; this kernel stores ONLY winner spikes
// (rare 4B stores, unique addresses) -> no zero-fill, no per-t barriers.
// x rows (h-1..h+1) staged 5 time steps at a time (12.2 KB LDS).
// Plain __launch_bounds__(256): VGPRs unconstrained so w[27]+mem[16] stay
// in registers (the rounds-2..4 spill disaster). Grid = B*H = 2048 x 256.
// ---------------------------------------------------------------------------
__global__ __launch_bounds__(256) void fused_kernel(
    const float* __restrict__ x,              // (T,B,3,64,64)
    const float* __restrict__ Wt,             // (64,3,3,3)
    const unsigned int* __restrict__ thr_raw, // (T,64)
    float* __restrict__ out)                  // (T,B,64,64,64) pre-zeroed
{
    __shared__ float sx[5][CIN][3][68];       // 12,240 B; rows 16B-aligned

    const int tid  = threadIdx.x;
    const int lane = tid & 63;                            // channel
    const int wave = tid >> 6;
    const int p0   = __builtin_amdgcn_readfirstlane(wave * 16);
    const int b    = blockIdx.x >> 6;
    const int h    = blockIdx.x & 63;

    float w[27];
    #pragma unroll
    for (int k = 0; k < 27; k++) w[k] = Wt[lane * 27 + k];

    const float* xb0 = x + (size_t)b * (CIN * HW);        // t=0 base, this b

#define STAGE5(T0) {                                                          \
        for (int l = tid; l < 5 * 594; l += 256) {                            \
            int t   = l / 594;                                                \
            int r0  = l - t * 594;                                            \
            int ci  = r0 / 198;                                               \
            int r1  = r0 - ci * 198;                                          \
            int r   = r1 / 66;                                                \
            int col = r1 - r * 66;                                            \
            int gh = h + r - 1;                                               \
            int gw = col - 1;                                                 \
            float v = 0.f;                                                    \
            if (gh >= 0 && gh < HH && gw >= 0 && gw < WW)                     \
                v = xb0[(size_t)((T0) + t) * ((size_t)BB * CIN * HW)          \
                        + ci * HW + gh * WW + gw];                            \
            sx[t][ci][r][col] = v;                                            \
        }                                                                     \
    }

    STAGE5(0);

    float mem[16];
    #pragma unroll
    for (int j = 0; j < 16; j++) mem[j] = 0.f;

    __syncthreads();   // first 5 t staged

    #pragma unroll 1
    for (int t = 0; t < TT; t++) {
        if (t == 5) {               // restage second half (only 2 barriers)
            __syncthreads();
            STAGE5(5);
            __syncthreads();
        }
        const int slot = (t < 5) ? t : t - 5;

        // per-lane (= per-channel) threshold constants (L2-resident 2.5 KB)
        float thr   = dec_f(thr_raw[t * COUT + lane]) + 1e-4f;
        float sinv  = 8.0f / thr;
        float s04   = 0.4f * thr;
        float sinh_ = INH * thr;

        int fmask = 0;     // bit j: this lane's channel fired at pixel p0+j

#define LIF_PX(J, ACC) {                                                    \
        float cur = fmaxf(ACC, 0.f);                                        \
        float z   = (cur - s04) * sinv;                                     \
        float sig = 1.0f / (1.0f + expf(-z));                               \
        float m   = mem[J] * DECAY + thr * sig;                             \
        int   sp  = m > thr;                                                \
        float score = sp ? m : 0.f;                                         \
        unsigned long long blt = __ballot(sp);                              \
        int fr = 0, sp_any = 0;                                             \
        if (blt) {   /* wave-uniform; rare */                               \
            float bs = score;                                               \
            int   bc = lane;                                                \
            _Pragma("unroll")                                               \
            for (int off = 32; off > 0; off >>= 1) {                        \
                float so = __shfl_xor(bs, off, 64);                         \
                int   co = __shfl_xor(bc, off, 64);                         \
                if (so > bs || (so == bs && co < bc)) { bs = so; bc = co; } \
            }                                                               \
            int spw = __shfl(sp, bc, 64);   /* winner's spike = any_sp */   \
            fr     = (lane == bc) && sp;                                    \
            sp_any = spw;                                                   \
        }                                                                   \
        mem[J] = fr ? 0.f : (m - (sp_any ? sinh_ : 0.f));                   \
        if (fr) fmask |= (1 << (J));                                        \
    }

        #pragma unroll
        for (int ch = 0; ch < 4; ch++) {       // 4-pixel chunks of this wave
            const int c0 = p0 + ch * 4;        // chunk start pixel
            float acc0 = 0.f, acc1 = 0.f, acc2 = 0.f, acc3 = 0.f;
            #pragma unroll
            for (int ci = 0; ci < CIN; ci++)
                #pragma unroll
                for (int kh = 0; kh < 3; kh++) {
                    // wave-uniform LDS reads: broadcast, conflict-free
                    const float* rp = &sx[slot][ci][kh][c0];
                    float4 q = *(const float4*)rp;
                    float2 r2 = *(const float2*)(rp + 4);
                    float x0 = q.x, x1 = q.y, x2 = q.z, x3 = q.w;
                    float x4 = r2.x, x5 = r2.y;
                    const float w0 = w[ci * 9 + kh * 3 + 0];
                    const float w1 = w[ci * 9 + kh * 3 + 1];
                    const float w2 = w[ci * 9 + kh * 3 + 2];
                    acc0 = fmaf(w0, x0, acc0); acc0 = fmaf(w1, x1, acc0); acc0 = fmaf(w2, x2, acc0);
                    acc1 = fmaf(w0, x1, acc1); acc1 = fmaf(w1, x2, acc1); acc1 = fmaf(w2, x3, acc1);
                    acc2 = fmaf(w0, x2, acc2); acc2 = fmaf(w1, x3, acc2); acc2 = fmaf(w2, x4, acc2);
                    acc3 = fmaf(w0, x3, acc3); acc3 = fmaf(w1, x4, acc3); acc3 = fmaf(w2, x5, acc3);
                }
            LIF_PX(ch * 4 + 0, acc0);
            LIF_PX(ch * 4 + 1, acc1);
            LIF_PX(ch * 4 + 2, acc2);
            LIF_PX(ch * 4 + 3, acc3);
        }
#undef LIF_PX

        // sparse winner stores (rare); out pre-zeroed by thr_kernel; each
        // address written by exactly one thread -> no ordering needed
        if (fmask) {
            float* os = out + (((size_t)t * BB + b) * COUT) * HW + h * WW;
            #pragma unroll
            for (int j = 0; j < 16; j++)
                if (fmask & (1 << j))
                    os[(size_t)lane * HW + p0 + j] = 1.0f;
        }
    }
#undef STAGE5
}

// ---------------------------------------------------------------------------
extern "C" void kernel_launch(void* const* d_in, const int* in_sizes, int n_in,
                              void* d_out, int out_size, void* d_ws, size_t ws_size,
                              hipStream_t stream) {
    const float* x = (const float*)d_in[0];   // (T,B,3,64,64)
    const float* W = (const float*)d_in[1];   // (64,3,3,3)
    float* out     = (float*)d_out;           // (T,B,64,64,64)

    unsigned int* thr = (unsigned int*)d_ws;  // (T,64) — only 2.5 KB of ws used
    hipMemsetAsync(thr, 0, TT * COUT * sizeof(unsigned int), stream);

    thr_kernel<<<dim3(HH / 4, BB, TT), 256, 0, stream>>>(x, W, thr, out);
    fused_kernel<<<dim3(BB * HH), 256, 0, stream>>>(x, W, thr, out);
}